// Round 9
// baseline (234.682 us; speedup 1.0000x reference)
//
#include <hip/hip_runtime.h>

#define B_    8
#define C_    64
#define H_    128
#define W_    128
#define K_    9
#define J_    18     // 2*K
#define COUT_ 64
#define TPX   16     // pixels per tile
#define CK    576    // C_*K_
#define SROW  584    // sbuf row stride (bf16 elems)
#define NW81  (C_ * 81)                 // 5184 packed weight words
#define L2E   1.4426950408889634f       // log2(e), folded into conv weights+bias

typedef __attribute__((ext_vector_type(8))) short short8;
typedef __attribute__((ext_vector_type(4))) float float4v;
typedef __attribute__((ext_vector_type(2))) float f32x2;

// round-to-nearest-even fp32 -> bf16 (used in precompute only)
__device__ __forceinline__ unsigned short f2bf(float f) {
    unsigned int u = __float_as_uint(f);
    u = u + 0x7fffu + ((u >> 16) & 1u);
    return (unsigned short)(u >> 16);
}

// conv tap (r*3+s) -> strip index r*7+s. constexpr everywhere (earlier:
// runtime-indexed S[] -> scratch demotion -> GB-scale spill).
constexpr int TMAP[9] = {0, 1, 2, 7, 8, 9, 14, 15, 16};

// -------- pre-kernel: NCHW->NHWC transpose + weight prep, one launch -----
#define TRBLK (B_ * H_ * 2)            // 2048
#define DWBLK ((CK * COUT_) / 256)     // 144
__global__ __launch_bounds__(256)
void pre_all(const float* __restrict__ x, float* __restrict__ xt,
             const float* __restrict__ dw, unsigned short* __restrict__ dwb,
             const float* __restrict__ ow, unsigned int* __restrict__ owp) {
    __shared__ float tile[64][65];
    const int bid = blockIdx.x;
    if (bid < TRBLK) {
        const int wt  = bid & 1;
        const int h   = (bid >> 1) & 127;
        const int b   = bid >> 8;
        const int w0  = wt << 6;
        const int q   = threadIdx.x >> 6;
        const int l   = threadIdx.x & 63;
        #pragma unroll
        for (int r = 0; r < 16; r++) {
            const int c = q * 16 + r;
            tile[c][l] = x[((size_t)(b * C_ + c) * H_ + h) * W_ + w0 + l];
        }
        __syncthreads();
        #pragma unroll
        for (int r = 0; r < 16; r++) {
            const int w = q * 16 + r;
            xt[((size_t)(b * H_ + h) * W_ + w0 + w) * C_ + l] = tile[l][w];
        }
    } else if (bid < TRBLK + DWBLK) {
        const int i = (bid - TRBLK) * 256 + threadIdx.x;
        dwb[i] = f2bf(dw[i]);
    } else {
        const int i = (bid - TRBLK - DWBLK) * 256 + threadIdx.x;
        if (i < NW81) {
            const int c = i / 81, r = i - c * 81;
            const int k = r / 9,  t = r - k * 9;
            const float* s = ow + c * 162 + k * 18 + t;   // (2k)*9 = k*18
            owp[i] = (unsigned int)f2bf(s[0] * L2E) |
                     ((unsigned int)f2bf(s[9] * L2E) << 16);
        }
    }
}

// standalone fallbacks (small-workspace paths)
__global__ __launch_bounds__(256)
void nchw_to_nhwc(const float* __restrict__ x, float* __restrict__ xt) {
    __shared__ float tile[64][65];
    const int bid = blockIdx.x;
    const int wt  = bid & 1;
    const int h   = (bid >> 1) & 127;
    const int b   = bid >> 8;
    const int w0  = wt << 6;
    const int q   = threadIdx.x >> 6;
    const int l   = threadIdx.x & 63;
    #pragma unroll
    for (int r = 0; r < 16; r++) {
        const int c = q * 16 + r;
        tile[c][l] = x[((size_t)(b * C_ + c) * H_ + h) * W_ + w0 + l];
    }
    __syncthreads();
    #pragma unroll
    for (int r = 0; r < 16; r++) {
        const int w = q * 16 + r;
        xt[((size_t)(b * H_ + h) * W_ + w0 + w) * C_ + l] = tile[l][w];
    }
}
__global__ __launch_bounds__(256)
void prep_dwb(const float* __restrict__ dw, unsigned short* __restrict__ dwb) {
    const int i = blockIdx.x * 256 + threadIdx.x;
    if (i < CK * COUT_) dwb[i] = f2bf(dw[i]);
}

// ---- conv inner loop: full unroll via template recursion. Word T = k*9+t
// holds the bf16 (dy,dx) weight pair of output-pair k, tap t. One
// v_pk_fma_f32 per pixel per word.
template<int T>
__device__ __forceinline__ void conv_steps(const unsigned int* __restrict__ owc,
                                           const float (&S)[28], f32x2 (&v2)[4][9]) {
    if constexpr (T < 81) {
        const unsigned int pw = owc[T];
        const f32x2 w2 = {__uint_as_float(pw << 16),
                          __uint_as_float(pw & 0xffff0000u)};
        constexpr int k = T / 9;
        constexpr int p = TMAP[T % 9];
        #pragma unroll
        for (int px = 0; px < 4; px++) {
            const float s = S[p + px];
            v2[px][k] = __builtin_elementwise_fma(w2, (f32x2){s, s}, v2[px][k]);
        }
        conv_steps<T + 1>(owc, S, v2);
    }
}

// ---- per-pixel bilinear taps ----
// (round-1 lesson): dy/dx are bilinear SAMPLE COORDINATES — cross term
// dy*dx + constant term, so 1/sum does NOT commute through the einsum.
// Normalize here: v_pk_mul_f32. RTZ bf16 store (hi-half) — 0 VALU,
// absmax unchanged at 0.03125 (r8 verified).
template<int I>
__device__ __forceinline__ void taps_px(const f32x2 (&w)[9], const f32x2 inv2,
                                        const float (&S)[28],
                                        unsigned short* __restrict__ sb) {
    #pragma unroll
    for (int k = 0; k < 9; k++) {
        const f32x2 d2 = w[k] * inv2;              // v_pk_mul_f32
        const float dy = d2.x;
        const float dx = d2.y;
        const int base = TMAP[k] + I;              // constexpr-folded
        const float a  = S[base],     bb = S[base + 1];
        const float c  = S[base + 7], dd = S[base + 8];
        const float top = fmaf(dx, bb - a, a);
        const float bot = fmaf(dx, dd - c, c);
        const float v   = fmaf(dy, bot - top, top);
        sb[k] = (unsigned short)(__float_as_uint(v) >> 16);   // RTZ hi-half
    }
}

// ---- 4x7 input strip load (rows h-1..h+2, cols wbase-1..wbase+5) ----
template<bool NHWC>
__device__ __forceinline__ void load_strip(const float* __restrict__ xsrc,
                                           int b, int h, int wbase, int lane,
                                           float (&S)[28]) {
    if (h >= 1 && h <= H_ - 3 && wbase >= 1 && wbase <= W_ - 6) {
        // interior fast path: bounds are wave-uniform -> scalar branch
        const float* p0 = NHWC
            ? xsrc + ((size_t)(b * H_ + (h - 1)) * W_ + (wbase - 1)) * C_ + lane
            : xsrc + ((size_t)(b * C_ + lane) * H_ + (h - 1)) * W_ + (wbase - 1);
        const int rs = NHWC ? (W_ * C_) : W_;
        const int cs = NHWC ? C_ : 1;
        #pragma unroll
        for (int r = 0; r < 4; r++)
            #pragma unroll
            for (int s = 0; s < 7; s++)
                S[r * 7 + s] = p0[r * rs + s * cs];
    } else {
        #pragma unroll
        for (int r = 0; r < 4; r++) {
            const int y = h - 1 + r;
            const bool yv = (unsigned)y < (unsigned)H_;
            #pragma unroll
            for (int s = 0; s < 7; s++) {
                const int xx = wbase - 1 + s;
                const bool ok = yv && ((unsigned)xx < (unsigned)W_);
                const float* p = NHWC
                    ? xsrc + ((size_t)(b * H_ + (y & 127)) * W_ + (xx & 127)) * C_ + lane
                    : xsrc + ((size_t)(b * C_ + lane) * H_ + (y & 127)) * W_ + (xx & 127);
                S[r * 7 + s] = ok ? *p : 0.0f;
            }
        }
    }
}

// ---- phase A: conv + exp2 + cross-lane reduce -> inv[4]; numerators in v2
__device__ __forceinline__ void phaseA(const unsigned int* __restrict__ owc,
                                       const float2* __restrict__ obp,
                                       const float (&S)[28],
                                       f32x2 (&v2)[4][9], float (&inv)[4]) {
    #pragma unroll
    for (int p = 0; p < 9; p++) {
        const float2 f = obp[p];                 // bias, L1-hot (4.6 KB)
        const f32x2 b2 = {f.x * L2E, f.y * L2E};
        v2[0][p] = b2; v2[1][p] = b2; v2[2][p] = b2; v2[3][p] = b2;
    }
    conv_steps<0>(owc, S, v2);

    // exp2 + per-px local sums via v_pk_add_f32. No max-subtraction: logits
    // bounded (|w|~0.05 scale), exp2 args ~ +-15, fp32-safe.
    float psum[4];
    #pragma unroll
    for (int px = 0; px < 4; px++) {
        f32x2 ps2 = {0.0f, 0.0f};
        #pragma unroll
        for (int k = 0; k < 9; k++) {
            f32x2 e;
            e.x = __builtin_amdgcn_exp2f(v2[px][k].x);
            e.y = __builtin_amdgcn_exp2f(v2[px][k].y);
            v2[px][k] = e;
            ps2 += e;                            // v_pk_add_f32
        }
        psum[px] = ps2.x + ps2.y;
    }

    // cross-lane softmax denominators (64 lanes x 18 = channel axis),
    // 4 px interleaved; xor<32 via single-inst ds_swizzle, xor32 via shfl.
    #pragma unroll
    for (int px = 0; px < 4; px++) psum[px] += __shfl_xor(psum[px], 32, 64);
#define RED_LEVEL(PAT) do { \
        const float r0_ = __uint_as_float((unsigned)__builtin_amdgcn_ds_swizzle((int)__float_as_uint(psum[0]), (PAT))); \
        const float r1_ = __uint_as_float((unsigned)__builtin_amdgcn_ds_swizzle((int)__float_as_uint(psum[1]), (PAT))); \
        const float r2_ = __uint_as_float((unsigned)__builtin_amdgcn_ds_swizzle((int)__float_as_uint(psum[2]), (PAT))); \
        const float r3_ = __uint_as_float((unsigned)__builtin_amdgcn_ds_swizzle((int)__float_as_uint(psum[3]), (PAT))); \
        psum[0] += r0_; psum[1] += r1_; psum[2] += r2_; psum[3] += r3_; \
    } while (0)
    RED_LEVEL(0x401F);   // xor 16
    RED_LEVEL(0x201F);   // xor 8
    RED_LEVEL(0x101F);   // xor 4
    RED_LEVEL(0x081F);   // xor 2
    RED_LEVEL(0x041F);   // xor 1
#undef RED_LEVEL

    inv[0] = __builtin_amdgcn_rcpf(psum[0]);
    inv[1] = __builtin_amdgcn_rcpf(psum[1]);
    inv[2] = __builtin_amdgcn_rcpf(psum[2]);
    inv[3] = __builtin_amdgcn_rcpf(psum[3]);
}

// ---- phase B: MFMA einsum. Per wave: 16 px x 16 outs, K=576.
// r9: dual accumulators break the 18-deep serial MFMA dependency chain
// (~16 cyc latency each); fp32 add at the end is exact.
template<bool PREB>
__device__ __forceinline__ void phaseB(const unsigned short* __restrict__ arow,
                                       const unsigned short* __restrict__ bbase,
                                       const float* __restrict__ brow0,
                                       float bias, float* __restrict__ outp) {
    float4v acc0 = {0.f, 0.f, 0.f, 0.f};
    float4v acc1 = {0.f, 0.f, 0.f, 0.f};
    #pragma unroll
    for (int t = 0; t < 18; t += 2) {
        short8 af0 = *(const short8*)(arow + t * 32);
        short8 af1 = *(const short8*)(arow + (t + 1) * 32);
        short8 bf0, bf1;
        if (PREB) {
            bf0 = *(const short8*)(bbase + t * 32);
            bf1 = *(const short8*)(bbase + (t + 1) * 32);
        } else {
            #pragma unroll
            for (int u = 0; u < 2; u++) {
                const float* brow = brow0 + (t + u) * 32;
                float4 b0 = *(const float4*)brow;
                float4 b1 = *(const float4*)(brow + 4);
                union { short8 s8; unsigned short uu[8]; } bfu;
                bfu.uu[0] = f2bf(b0.x); bfu.uu[1] = f2bf(b0.y); bfu.uu[2] = f2bf(b0.z); bfu.uu[3] = f2bf(b0.w);
                bfu.uu[4] = f2bf(b1.x); bfu.uu[5] = f2bf(b1.y); bfu.uu[6] = f2bf(b1.z); bfu.uu[7] = f2bf(b1.w);
                if (u == 0) bf0 = bfu.s8; else bf1 = bfu.s8;
            }
        }
        acc0 = __builtin_amdgcn_mfma_f32_16x16x32_bf16(af0, bf0, acc0, 0, 0, 0);
        acc1 = __builtin_amdgcn_mfma_f32_16x16x32_bf16(af1, bf1, acc1, 0, 0, 0);
    }
    float4 res;
    res.x = (acc0[0] + acc1[0]) + bias; res.y = (acc0[1] + acc1[1]) + bias;
    res.z = (acc0[2] + acc1[2]) + bias; res.w = (acc0[3] + acc1[3]) + bias;
    *(float4*)outp = res;
}

// -------- fused kernel: 512 threads = 2 independent 4-wave pixel-groups --
// r3/r4/r7 lesson (3x): ANY tile-loop wrapper demotes locals to scratch.
// r8 lesson: VALU-inst cuts have elasticity ~0.15; residual limiter is
// per-block fixed cost x 16 sequential blocks/CU (stage 20.7KB, barriers,
// drains) at 28% measured occupancy. Loop-free amortization: 2 pixel-
// groups per block (waves 0-3 / 4-7), disjoint sbuf halves, shared ow_s.
// 2048 blocks of 64 px -> 8 sequential blocks/CU, fixed costs halved.
// LDS 20736 + 2*18688 = 58112 B -> 2 blocks/CU (16 waves, 50% cap).
// r6 lesson: tight launch-bounds snap the reg budget down -> spill;
// (512,3) gives ~170-reg budget, compiler needs ~84.
template<bool NHWC, bool PREB, bool PREP>
__global__ __launch_bounds__(512, 3)
void dcn_fused(const float* __restrict__ xsrc,
               const float* __restrict__ ow,
               const unsigned int* __restrict__ owp,
               const float* __restrict__ ob,
               const float* __restrict__ dw,
               const unsigned short* __restrict__ dwb,
               const float* __restrict__ db,
               float* __restrict__ out) {
    __shared__ __align__(16) unsigned int ow_s[NW81];                 // 20736 B
    __shared__ __align__(16) unsigned short sbuf[2 * TPX * SROW];     // 37376 B

    const int tid  = threadIdx.x;
    const int w8   = tid >> 6;           // 0..7
    const int lane = tid & 63;
    const int grp  = w8 >> 2;            // pixel-group 0/1
    const int wl   = w8 & 3;             // wave within group

    // 2048 blocks: bid&7 = image = XCD (round-robin); bid>>3 = h*2 + half.
    const int bid  = blockIdx.x;
    const int b    = bid & 7;
    const int rem  = bid >> 3;           // 0..255
    const int h    = rem >> 1;
    const int gbase = ((rem & 1) << 6) + (grp << 5);   // 0/32/64/96

    // stage packed offset weights (shared by both groups, 8 tiles total)
    if (PREP) {
        #pragma unroll
        for (int i = 0; i < 10; i++)
            ow_s[tid + i * 512] = owp[tid + i * 512];   // 5120, coalesced
        if (tid < 64) ow_s[5120 + tid] = owp[5120 + tid];
    } else {
        for (int i = tid; i < NW81; i += 512) {      // fallback: pack in-kernel
            const int c = i / 81, r = i - c * 81;
            const int k = r / 9,  t = r - k * 9;
            const float* s = ow + c * 162 + k * 18 + t;
            ow_s[i] = (unsigned int)f2bf(s[0] * L2E) |
                      ((unsigned int)f2bf(s[9] * L2E) << 16);
        }
    }

    // hoisted invariant locals (plain scalars/pointers, no struct)
    const int quad = lane >> 4;
    const int o    = (wl << 4) + (lane & 15);
    const unsigned int* owc = ow_s + lane * 81;
    const float2* obp = (const float2*)(ob + lane * J_);
    unsigned short* gsb = sbuf + grp * (TPX * SROW);
    const unsigned short* arow  = gsb + (lane & 15) * SROW + quad * 8;
    const unsigned short* bbase = PREB ? (dwb + (size_t)o * CK + quad * 8) : nullptr;
    const float* brow0 = PREB ? nullptr : (dw + (size_t)o * CK + quad * 8);
    const float bias = db[o];
    float* outrow = out + ((size_t)(b * COUT_ + o) * H_ + h) * W_ + gbase + (quad << 2);
    unsigned short* sb = gsb + (wl << 2) * SROW + lane * K_;

    // tile-0 strip: issue before the staging barrier (overlaps staging)
    float S0[28];
    load_strip<NHWC>(xsrc, b, h, gbase + (wl << 2), lane, S0);

    __syncthreads();

    // ================= tile 0 =================
    f32x2 v2a[4][9];
    float inva[4];
    phaseA(owc, obp, S0, v2a, inva);
    taps_px<0>(v2a[0], (f32x2){inva[0], inva[0]}, S0, sb);
    taps_px<1>(v2a[1], (f32x2){inva[1], inva[1]}, S0, sb + SROW);
    taps_px<2>(v2a[2], (f32x2){inva[2], inva[2]}, S0, sb + 2 * SROW);
    taps_px<3>(v2a[3], (f32x2){inva[3], inva[3]}, S0, sb + 3 * SROW);

    __syncthreads();

    // tile-1 strip loads first (long latency, covered by phase-B0 below)
    float S1[28];
    load_strip<NHWC>(xsrc, b, h, gbase + 16 + (wl << 2), lane, S1);

    // phase B of tile 0 (MFMA pipe) ...
    phaseB<PREB>(arow, bbase, brow0, bias, outrow);

    // ... overlapped (same region, no barrier) with tile-1 conv (VALU pipe);
    // B0's store drains at the next barrier after ~phaseA1-duration -> hidden.
    f32x2 v2b[4][9];
    float invb[4];
    phaseA(owc, obp, S1, v2b, invb);

    __syncthreads();   // all waves done reading sbuf in phase-B0

    // ================= tile 1 =================
    taps_px<0>(v2b[0], (f32x2){invb[0], invb[0]}, S1, sb);
    taps_px<1>(v2b[1], (f32x2){invb[1], invb[1]}, S1, sb + SROW);
    taps_px<2>(v2b[2], (f32x2){invb[2], invb[2]}, S1, sb + 2 * SROW);
    taps_px<3>(v2b[3], (f32x2){invb[3], invb[3]}, S1, sb + 3 * SROW);

    __syncthreads();

    phaseB<PREB>(arow, bbase, brow0, bias, outrow + 16);
}

extern "C" void kernel_launch(void* const* d_in, const int* in_sizes, int n_in,
                              void* d_out, int out_size, void* d_ws, size_t ws_size,
                              hipStream_t stream) {
    (void)in_sizes; (void)n_in; (void)out_size;
    const float* x  = (const float*)d_in[0];
    const float* ow = (const float*)d_in[1];
    const float* ob = (const float*)d_in[2];
    const float* dw = (const float*)d_in[3];
    const float* db = (const float*)d_in[4];
    float* outp = (float*)d_out;

    const size_t xbytes  = (size_t)B_ * C_ * H_ * W_ * sizeof(float);
    const size_t dwbytes = (size_t)CK * COUT_ * sizeof(unsigned short);
    const size_t owbytes = (size_t)NW81 * sizeof(unsigned int);
    const dim3 grid(B_ * H_ * 2), blk512(512), blk256(256);  // 2048 x 512
    const int owblocks = (NW81 + 255) / 256;     // 21

    if (ws_size >= xbytes + dwbytes + owbytes) {
        float* xt = (float*)d_ws;
        unsigned short* dwb = (unsigned short*)((char*)d_ws + xbytes);
        unsigned int* owp = (unsigned int*)((char*)d_ws + xbytes + dwbytes);
        pre_all<<<dim3(TRBLK + DWBLK + owblocks), blk256, 0, stream>>>(x, xt, dw, dwb, ow, owp);
        dcn_fused<true, true, true><<<grid, blk512, 0, stream>>>(xt, ow, owp, ob, dw, dwb, db, outp);
    } else if (ws_size >= xbytes + dwbytes) {
        float* xt = (float*)d_ws;
        unsigned short* dwb = (unsigned short*)((char*)d_ws + xbytes);
        nchw_to_nhwc<<<dim3(B_ * H_ * 2), blk256, 0, stream>>>(x, xt);
        prep_dwb<<<dim3((CK * COUT_ + 255) / 256), blk256, 0, stream>>>(dw, dwb);
        dcn_fused<true, true, false><<<grid, blk512, 0, stream>>>(xt, ow, nullptr, ob, dw, dwb, db, outp);
    } else if (ws_size >= xbytes) {
        float* xt = (float*)d_ws;
        nchw_to_nhwc<<<dim3(B_ * H_ * 2), blk256, 0, stream>>>(x, xt);
        dcn_fused<true, false, false><<<grid, blk512, 0, stream>>>(xt, ow, nullptr, ob, dw, nullptr, db, outp);
    } else {
        dcn_fused<false, false, false><<<grid, blk512, 0, stream>>>(x, ow, nullptr, ob, dw, nullptr, db, outp);
    }
}

// Round 10
// 190.807 us; speedup vs baseline: 1.2299x; 1.2299x over previous
//
#include <hip/hip_runtime.h>

#define B_    8
#define C_    64
#define H_    128
#define W_    128
#define K_    9
#define J_    18     // 2*K
#define COUT_ 64
#define TPX   16     // pixels per tile
#define CK    576    // C_*K_
#define SROW  584    // sbuf row stride (bf16 elems)
#define NW81  (C_ * 81)                 // 5184 packed weight words
#define L2E   1.4426950408889634f       // log2(e), folded into conv weights+bias

typedef __attribute__((ext_vector_type(8))) short short8;
typedef __attribute__((ext_vector_type(4))) float float4v;
typedef __attribute__((ext_vector_type(2))) float f32x2;

// round-to-nearest-even fp32 -> bf16 (used in precompute only)
__device__ __forceinline__ unsigned short f2bf(float f) {
    unsigned int u = __float_as_uint(f);
    u = u + 0x7fffu + ((u >> 16) & 1u);
    return (unsigned short)(u >> 16);
}

// conv tap (r*3+s) -> strip index r*7+s. constexpr everywhere (earlier:
// runtime-indexed S[] -> scratch demotion -> GB-scale spill).
constexpr int TMAP[9] = {0, 1, 2, 7, 8, 9, 14, 15, 16};

// -------- pre-kernel: NCHW->NHWC transpose + weight prep, one launch -----
#define TRBLK (B_ * H_ * 2)            // 2048
#define DWBLK ((CK * COUT_) / 256)     // 144
__global__ __launch_bounds__(256)
void pre_all(const float* __restrict__ x, float* __restrict__ xt,
             const float* __restrict__ dw, unsigned short* __restrict__ dwb,
             const float* __restrict__ ow, unsigned int* __restrict__ owp) {
    __shared__ float tile[64][65];
    const int bid = blockIdx.x;
    if (bid < TRBLK) {
        const int wt  = bid & 1;
        const int h   = (bid >> 1) & 127;
        const int b   = bid >> 8;
        const int w0  = wt << 6;
        const int q   = threadIdx.x >> 6;
        const int l   = threadIdx.x & 63;
        #pragma unroll
        for (int r = 0; r < 16; r++) {
            const int c = q * 16 + r;
            tile[c][l] = x[((size_t)(b * C_ + c) * H_ + h) * W_ + w0 + l];
        }
        __syncthreads();
        #pragma unroll
        for (int r = 0; r < 16; r++) {
            const int w = q * 16 + r;
            xt[((size_t)(b * H_ + h) * W_ + w0 + w) * C_ + l] = tile[l][w];
        }
    } else if (bid < TRBLK + DWBLK) {
        const int i = (bid - TRBLK) * 256 + threadIdx.x;
        dwb[i] = f2bf(dw[i]);
    } else {
        const int i = (bid - TRBLK - DWBLK) * 256 + threadIdx.x;
        if (i < NW81) {
            const int c = i / 81, r = i - c * 81;
            const int k = r / 9,  t = r - k * 9;
            const float* s = ow + c * 162 + k * 18 + t;   // (2k)*9 = k*18
            owp[i] = (unsigned int)f2bf(s[0] * L2E) |
                     ((unsigned int)f2bf(s[9] * L2E) << 16);
        }
    }
}

// standalone fallbacks (small-workspace paths)
__global__ __launch_bounds__(256)
void nchw_to_nhwc(const float* __restrict__ x, float* __restrict__ xt) {
    __shared__ float tile[64][65];
    const int bid = blockIdx.x;
    const int wt  = bid & 1;
    const int h   = (bid >> 1) & 127;
    const int b   = bid >> 8;
    const int w0  = wt << 6;
    const int q   = threadIdx.x >> 6;
    const int l   = threadIdx.x & 63;
    #pragma unroll
    for (int r = 0; r < 16; r++) {
        const int c = q * 16 + r;
        tile[c][l] = x[((size_t)(b * C_ + c) * H_ + h) * W_ + w0 + l];
    }
    __syncthreads();
    #pragma unroll
    for (int r = 0; r < 16; r++) {
        const int w = q * 16 + r;
        xt[((size_t)(b * H_ + h) * W_ + w0 + w) * C_ + l] = tile[l][w];
    }
}
__global__ __launch_bounds__(256)
void prep_dwb(const float* __restrict__ dw, unsigned short* __restrict__ dwb) {
    const int i = blockIdx.x * 256 + threadIdx.x;
    if (i < CK * COUT_) dwb[i] = f2bf(dw[i]);
}

// ---- conv inner loop: full unroll via template recursion. Word T = k*9+t
// holds the bf16 (dy,dx) weight pair of output-pair k, tap t. One
// v_pk_fma_f32 per pixel per word.
template<int T>
__device__ __forceinline__ void conv_steps(const unsigned int* __restrict__ owc,
                                           const float (&S)[28], f32x2 (&v2)[4][9]) {
    if constexpr (T < 81) {
        const unsigned int pw = owc[T];
        const f32x2 w2 = {__uint_as_float(pw << 16),
                          __uint_as_float(pw & 0xffff0000u)};
        constexpr int k = T / 9;
        constexpr int p = TMAP[T % 9];
        #pragma unroll
        for (int px = 0; px < 4; px++) {
            const float s = S[p + px];
            v2[px][k] = __builtin_elementwise_fma(w2, (f32x2){s, s}, v2[px][k]);
        }
        conv_steps<T + 1>(owc, S, v2);
    }
}

// ---- per-pixel bilinear taps ----
// (round-1 lesson): dy/dx are bilinear SAMPLE COORDINATES — cross term
// dy*dx + constant term, so 1/sum does NOT commute through the einsum.
// Normalize here: v_pk_mul_f32. RTZ bf16 store (hi-half) — 0 VALU,
// absmax unchanged at 0.03125 (r8 verified).
template<int I>
__device__ __forceinline__ void taps_px(const f32x2 (&w)[9], const f32x2 inv2,
                                        const float (&S)[28],
                                        unsigned short* __restrict__ sb) {
    #pragma unroll
    for (int k = 0; k < 9; k++) {
        const f32x2 d2 = w[k] * inv2;              // v_pk_mul_f32
        const float dy = d2.x;
        const float dx = d2.y;
        const int base = TMAP[k] + I;              // constexpr-folded
        const float a  = S[base],     bb = S[base + 1];
        const float c  = S[base + 7], dd = S[base + 8];
        const float top = fmaf(dx, bb - a, a);
        const float bot = fmaf(dx, dd - c, c);
        const float v   = fmaf(dy, bot - top, top);
        sb[k] = (unsigned short)(__float_as_uint(v) >> 16);   // RTZ hi-half
    }
}

// ---- 4x7 input strip load (rows h-1..h+2, cols wbase-1..wbase+5) ----
template<bool NHWC>
__device__ __forceinline__ void load_strip(const float* __restrict__ xsrc,
                                           int b, int h, int wbase, int lane,
                                           float (&S)[28]) {
    if (h >= 1 && h <= H_ - 3 && wbase >= 1 && wbase <= W_ - 6) {
        // interior fast path: bounds are wave-uniform -> scalar branch
        const float* p0 = NHWC
            ? xsrc + ((size_t)(b * H_ + (h - 1)) * W_ + (wbase - 1)) * C_ + lane
            : xsrc + ((size_t)(b * C_ + lane) * H_ + (h - 1)) * W_ + (wbase - 1);
        const int rs = NHWC ? (W_ * C_) : W_;
        const int cs = NHWC ? C_ : 1;
        #pragma unroll
        for (int r = 0; r < 4; r++)
            #pragma unroll
            for (int s = 0; s < 7; s++)
                S[r * 7 + s] = p0[r * rs + s * cs];
    } else {
        #pragma unroll
        for (int r = 0; r < 4; r++) {
            const int y = h - 1 + r;
            const bool yv = (unsigned)y < (unsigned)H_;
            #pragma unroll
            for (int s = 0; s < 7; s++) {
                const int xx = wbase - 1 + s;
                const bool ok = yv && ((unsigned)xx < (unsigned)W_);
                const float* p = NHWC
                    ? xsrc + ((size_t)(b * H_ + (y & 127)) * W_ + (xx & 127)) * C_ + lane
                    : xsrc + ((size_t)(b * C_ + lane) * H_ + (y & 127)) * W_ + (xx & 127);
                S[r * 7 + s] = ok ? *p : 0.0f;
            }
        }
    }
}

// ---- DPP butterfly add: v_add_f32 with a DPP-permuted operand (VALU,
// ~4 cyc, no DS round-trip). bound_ctrl=1, full row/bank masks.
// 0xB1 = quad_perm [1,0,3,2] (xor1), 0x4E = quad_perm [2,3,0,1] (xor2),
// 0x141 = row_half_mirror (combines 4-sums into 8), 0x140 = row_mirror
// (combines 8-sums into 16).
template<int CTRL>
__device__ __forceinline__ float dpp_add(float v) {
    const int t = __builtin_amdgcn_update_dpp(0, __float_as_int(v),
                                              CTRL, 0xF, 0xF, true);
    return v + __int_as_float(t);
}

// ---- phase A: conv + exp2 + cross-lane reduce -> inv[4]; numerators in v2
__device__ __forceinline__ void phaseA(const unsigned int* __restrict__ owc,
                                       const float2* __restrict__ obp,
                                       const float (&S)[28],
                                       f32x2 (&v2)[4][9], float (&inv)[4]) {
    #pragma unroll
    for (int p = 0; p < 9; p++) {
        const float2 f = obp[p];                 // bias, L1-hot (4.6 KB)
        const f32x2 b2 = {f.x * L2E, f.y * L2E};
        v2[0][p] = b2; v2[1][p] = b2; v2[2][p] = b2; v2[3][p] = b2;
    }
    conv_steps<0>(owc, S, v2);

    // exp2 + per-px local sums via v_pk_add_f32. No max-subtraction: logits
    // bounded (|w|~0.05 scale), exp2 args ~ +-15, fp32-safe.
    float psum[4];
    #pragma unroll
    for (int px = 0; px < 4; px++) {
        f32x2 ps2 = {0.0f, 0.0f};
        #pragma unroll
        for (int k = 0; k < 9; k++) {
            f32x2 e;
            e.x = __builtin_amdgcn_exp2f(v2[px][k].x);
            e.y = __builtin_amdgcn_exp2f(v2[px][k].y);
            v2[px][k] = e;
            ps2 += e;                            // v_pk_add_f32
        }
        psum[px] = ps2.x + ps2.y;
    }

    // cross-lane softmax denominators (64 lanes x 18 = channel axis).
    // r10: 4 low levels via DPP VALU adds (no DS latency); only xor16
    // (ds_swizzle, intra-32) + xor32 (shfl) touch the DS pipe.
    // DS hops per px: 6 -> 2; 4 px interleaved.
    #pragma unroll
    for (int px = 0; px < 4; px++) {
        float s = psum[px];
        s = dpp_add<0xB1>(s);     // xor1  (quad_perm)
        s = dpp_add<0x4E>(s);     // xor2  (quad_perm)
        s = dpp_add<0x141>(s);    // 4->8  (row_half_mirror)
        s = dpp_add<0x140>(s);    // 8->16 (row_mirror)
        psum[px] = s;
    }
    // xor16 within each 32-lane group (ds_swizzle is intra-32 only)
    {
        const float r0_ = __uint_as_float((unsigned)__builtin_amdgcn_ds_swizzle((int)__float_as_uint(psum[0]), 0x401F));
        const float r1_ = __uint_as_float((unsigned)__builtin_amdgcn_ds_swizzle((int)__float_as_uint(psum[1]), 0x401F));
        const float r2_ = __uint_as_float((unsigned)__builtin_amdgcn_ds_swizzle((int)__float_as_uint(psum[2]), 0x401F));
        const float r3_ = __uint_as_float((unsigned)__builtin_amdgcn_ds_swizzle((int)__float_as_uint(psum[3]), 0x401F));
        psum[0] += r0_; psum[1] += r1_; psum[2] += r2_; psum[3] += r3_;
    }
    // xor32 across the two 32-lane halves
    #pragma unroll
    for (int px = 0; px < 4; px++) psum[px] += __shfl_xor(psum[px], 32, 64);

    inv[0] = __builtin_amdgcn_rcpf(psum[0]);
    inv[1] = __builtin_amdgcn_rcpf(psum[1]);
    inv[2] = __builtin_amdgcn_rcpf(psum[2]);
    inv[3] = __builtin_amdgcn_rcpf(psum[3]);
}

// ---- phase B: MFMA einsum. Per wave: 16 px x 16 outs, K=576.
// r10: dual accumulators break the 18-deep serial MFMA dependency chain
// (~16 cyc latency each); fp32 add at the end is exact.
template<bool PREB>
__device__ __forceinline__ void phaseB(const unsigned short* __restrict__ arow,
                                       const unsigned short* __restrict__ bbase,
                                       const float* __restrict__ brow0,
                                       float bias, float* __restrict__ outp) {
    float4v acc0 = {0.f, 0.f, 0.f, 0.f};
    float4v acc1 = {0.f, 0.f, 0.f, 0.f};
    #pragma unroll
    for (int t = 0; t < 18; t += 2) {
        short8 af0 = *(const short8*)(arow + t * 32);
        short8 af1 = *(const short8*)(arow + (t + 1) * 32);
        short8 bf0, bf1;
        if (PREB) {
            bf0 = *(const short8*)(bbase + t * 32);
            bf1 = *(const short8*)(bbase + (t + 1) * 32);
        } else {
            #pragma unroll
            for (int u = 0; u < 2; u++) {
                const float* brow = brow0 + (t + u) * 32;
                float4 b0 = *(const float4*)brow;
                float4 b1 = *(const float4*)(brow + 4);
                union { short8 s8; unsigned short uu[8]; } bfu;
                bfu.uu[0] = f2bf(b0.x); bfu.uu[1] = f2bf(b0.y); bfu.uu[2] = f2bf(b0.z); bfu.uu[3] = f2bf(b0.w);
                bfu.uu[4] = f2bf(b1.x); bfu.uu[5] = f2bf(b1.y); bfu.uu[6] = f2bf(b1.z); bfu.uu[7] = f2bf(b1.w);
                if (u == 0) bf0 = bfu.s8; else bf1 = bfu.s8;
            }
        }
        acc0 = __builtin_amdgcn_mfma_f32_16x16x32_bf16(af0, bf0, acc0, 0, 0, 0);
        acc1 = __builtin_amdgcn_mfma_f32_16x16x32_bf16(af1, bf1, acc1, 0, 0, 0);
    }
    float4 res;
    res.x = (acc0[0] + acc1[0]) + bias; res.y = (acc0[1] + acc1[1]) + bias;
    res.z = (acc0[2] + acc1[2]) + bias; res.w = (acc0[3] + acc1[3]) + bias;
    *(float4*)outp = res;
}

// -------- fused kernel: 2 tiles (32 px) per block, FLAT straight-line -----
// r3/r4/r7 lesson (3x): ANY tile-loop wrapper demotes locals to scratch ->
// 100-400 MB spill traffic. Only this fully flat body compiles clean.
// r6 lesson: tighter launch-bounds snap the reg budget down -> spill; (256,3).
// r9 lesson: 512-thread twin-group blocks couple independent work behind
// 8-wave barriers and halve resident blocks -> -48%. Keep 256/4-wave shape.
template<bool NHWC, bool PREB, bool PREP>
__global__ __launch_bounds__(256, 3)
void dcn_fused(const float* __restrict__ xsrc,
               const float* __restrict__ ow,
               const unsigned int* __restrict__ owp,
               const float* __restrict__ ob,
               const float* __restrict__ dw,
               const unsigned short* __restrict__ dwb,
               const float* __restrict__ db,
               float* __restrict__ out) {
    __shared__ __align__(16) unsigned int ow_s[NW81];             // 20736 B
    __shared__ __align__(16) unsigned short sbuf[TPX * SROW];     // 18688 B

    const int tid  = threadIdx.x;
    const int wave = tid >> 6;
    const int lane = tid & 63;

    // XCD-chunked bijective swizzle (4096 blocks, 8 XCDs, 512 each):
    // XCD x gets all tiles of image x -> its xt slice + dwb live in L2.
    const int bid     = blockIdx.x;
    const int logical = (bid & 7) * 512 + (bid >> 3);
    const int b       = logical >> 9;
    const int rem     = logical & 511;
    const int h       = rem >> 2;
    const int w0base  = (rem & 3) << 5;           // 0/32/64/96; tiles at +0,+16

    // stage packed offset weights (once per 2 tiles)
    if (PREP) {
        #pragma unroll
        for (int i = 0; i < 20; i++)
            ow_s[tid + i * 256] = owp[tid + i * 256];   // coalesced u32 copy
        if (tid < 64) ow_s[5120 + tid] = owp[5120 + tid];
    } else {
        for (int i = tid; i < NW81; i += 256) {      // fallback: pack in-kernel
            const int c = i / 81, r = i - c * 81;
            const int k = r / 9,  t = r - k * 9;
            const float* s = ow + c * 162 + k * 18 + t;
            ow_s[i] = (unsigned int)f2bf(s[0] * L2E) |
                      ((unsigned int)f2bf(s[9] * L2E) << 16);
        }
    }

    // hoisted tile-invariant locals (plain scalars/pointers, no struct)
    const int quad = lane >> 4;
    const int o    = (wave << 4) + (lane & 15);
    const unsigned int* owc = ow_s + lane * 81;
    const float2* obp = (const float2*)(ob + lane * J_);
    const unsigned short* arow  = sbuf + (lane & 15) * SROW + quad * 8;
    const unsigned short* bbase = PREB ? (dwb + (size_t)o * CK + quad * 8) : nullptr;
    const float* brow0 = PREB ? nullptr : (dw + (size_t)o * CK + quad * 8);
    const float bias = db[o];
    float* outrow = out + ((size_t)(b * COUT_ + o) * H_ + h) * W_ + w0base + (quad << 2);
    unsigned short* sb = sbuf + (wave << 2) * SROW + lane * K_;

    // tile-0 strip: issue before the staging barrier (overlaps staging)
    float S0[28];
    load_strip<NHWC>(xsrc, b, h, w0base + (wave << 2), lane, S0);

    __syncthreads();

    // ================= tile 0 =================
    f32x2 v2a[4][9];
    float inva[4];
    phaseA(owc, obp, S0, v2a, inva);
    taps_px<0>(v2a[0], (f32x2){inva[0], inva[0]}, S0, sb);
    taps_px<1>(v2a[1], (f32x2){inva[1], inva[1]}, S0, sb + SROW);
    taps_px<2>(v2a[2], (f32x2){inva[2], inva[2]}, S0, sb + 2 * SROW);
    taps_px<3>(v2a[3], (f32x2){inva[3], inva[3]}, S0, sb + 3 * SROW);

    __syncthreads();

    // tile-1 strip loads first (long latency, covered by phase-B0 below)
    float S1[28];
    load_strip<NHWC>(xsrc, b, h, w0base + 16 + (wave << 2), lane, S1);

    // phase B of tile 0 (MFMA pipe) ...
    phaseB<PREB>(arow, bbase, brow0, bias, outrow);

    // ... overlapped (same region, no barrier) with tile-1 conv (VALU pipe)
    f32x2 v2b[4][9];
    float invb[4];
    phaseA(owc, obp, S1, v2b, invb);

    __syncthreads();   // all waves done reading sbuf in phase-B0

    // ================= tile 1 =================
    taps_px<0>(v2b[0], (f32x2){invb[0], invb[0]}, S1, sb);
    taps_px<1>(v2b[1], (f32x2){invb[1], invb[1]}, S1, sb + SROW);
    taps_px<2>(v2b[2], (f32x2){invb[2], invb[2]}, S1, sb + 2 * SROW);
    taps_px<3>(v2b[3], (f32x2){invb[3], invb[3]}, S1, sb + 3 * SROW);

    __syncthreads();

    phaseB<PREB>(arow, bbase, brow0, bias, outrow + 16);
}

extern "C" void kernel_launch(void* const* d_in, const int* in_sizes, int n_in,
                              void* d_out, int out_size, void* d_ws, size_t ws_size,
                              hipStream_t stream) {
    (void)in_sizes; (void)n_in; (void)out_size;
    const float* x  = (const float*)d_in[0];
    const float* ow = (const float*)d_in[1];
    const float* ob = (const float*)d_in[2];
    const float* dw = (const float*)d_in[3];
    const float* db = (const float*)d_in[4];
    float* outp = (float*)d_out;

    const size_t xbytes  = (size_t)B_ * C_ * H_ * W_ * sizeof(float);
    const size_t dwbytes = (size_t)CK * COUT_ * sizeof(unsigned short);
    const size_t owbytes = (size_t)NW81 * sizeof(unsigned int);
    const dim3 grid(B_ * H_ * 4), blk(256);      // 4096 blocks, 2 tiles each
    const int owblocks = (NW81 + 255) / 256;     // 21

    if (ws_size >= xbytes + dwbytes + owbytes) {
        float* xt = (float*)d_ws;
        unsigned short* dwb = (unsigned short*)((char*)d_ws + xbytes);
        unsigned int* owp = (unsigned int*)((char*)d_ws + xbytes + dwbytes);
        pre_all<<<dim3(TRBLK + DWBLK + owblocks), blk, 0, stream>>>(x, xt, dw, dwb, ow, owp);
        dcn_fused<true, true, true><<<grid, blk, 0, stream>>>(xt, ow, owp, ob, dw, dwb, db, outp);
    } else if (ws_size >= xbytes + dwbytes) {
        float* xt = (float*)d_ws;
        unsigned short* dwb = (unsigned short*)((char*)d_ws + xbytes);
        nchw_to_nhwc<<<dim3(B_ * H_ * 2), blk, 0, stream>>>(x, xt);
        prep_dwb<<<dim3((CK * COUT_ + 255) / 256), blk, 0, stream>>>(dw, dwb);
        dcn_fused<true, true, false><<<grid, blk, 0, stream>>>(xt, ow, nullptr, ob, dw, dwb, db, outp);
    } else if (ws_size >= xbytes) {
        float* xt = (float*)d_ws;
        nchw_to_nhwc<<<dim3(B_ * H_ * 2), blk, 0, stream>>>(x, xt);
        dcn_fused<true, false, false><<<grid, blk, 0, stream>>>(xt, ow, nullptr, ob, dw, nullptr, db, outp);
    } else {
        dcn_fused<false, false, false><<<grid, blk, 0, stream>>>(x, ow, nullptr, ob, dw, nullptr, db, outp);
    }
}